// Round 14
// baseline (266.927 us; speedup 1.0000x reference)
//
#include <hip/hip_runtime.h>
#include <hip/hip_bf16.h>
#include <math.h>

#define NB 4096
#define NC 8192
#define ND 128
#define NSPLIT 16
#define CPS (NC / NSPLIT)
#define NTILES (CPS / 16)
#define NEGINF -3.0e38f

#define WS_XN 16
#define WS_CN (WS_XN + NB)
#define WS_POS (WS_CN + NC)
#define WS_PART (WS_POS + NB)
#define WS_XB (WS_PART + NB * NSPLIT * 10)
#define WS_CB (WS_XB + NB * ND / 2)

typedef __attribute__((ext_vector_type(8))) short short8v;
typedef __attribute__((ext_vector_type(4))) float f32x4;

__global__ __launch_bounds__(256) void prep_kernel(
    const float* __restrict__ x, const float* __restrict__ c, float* __restrict__ ws) {
  if (blockIdx.x == 0 && threadIdx.x < 16) ws[threadIdx.x] = 0.0f;
  int wid = threadIdx.x >> 6, lane = threadIdx.x & 63;
  int row = blockIdx.x * 4 + wid;
  const float* src;
  float* ndst;
  ushort* bdst;
  if (row < NB) {
    src = x + (size_t)row * ND;
    ndst = ws + WS_XN + row;
    bdst = (ushort*)(ws + WS_XB) + (size_t)row * ND;
  } else {
    int r = row - NB;
    src = c + (size_t)r * ND;
    ndst = ws + WS_CN + r;
    bdst = (ushort*)(ws + WS_CB) + (size_t)r * ND;
  }
  float2 v = *(const float2*)(src + lane * 2);
  __hip_bfloat16 h0 = __float2bfloat16(v.x);
  __hip_bfloat16 h1 = __float2bfloat16(v.y);
  ushort2 u;
  u.x = *(ushort*)&h0;
  u.y = *(ushort*)&h1;
  *(ushort2*)(bdst + lane * 2) = u;
  float s = fmaf(v.x, v.x, v.y * v.y);
#pragma unroll
  for (int off = 32; off; off >>= 1) s += __shfl_down(s, off, 64);
  if (lane == 0) *ndst = s;
}

#define INS10(arr, val)                          \
  {                                              \
    float _v = (val);                            \
    _Pragma("unroll") for (int _k = 0; _k < 10; ++_k) { \
      float _mx = fmaxf(arr[_k], _v);            \
      _v = fminf(arr[_k], _v);                   \
      arr[_k] = _mx;                             \
    }                                            \
  }

#define SW(a, b) { float _x = fmaxf(a, b); b = fminf(a, b); a = _x; }

#define LOADF(d0, d1, d2, d3, IDX)                                            \
  {                                                                           \
    const ushort* cp_ = cb + (size_t)(cbase + (IDX) * 16 + lo) * ND + hi * 8; \
    d0 = *(const short8v*)(cp_ + 0);                                          \
    d1 = *(const short8v*)(cp_ + 32);                                         \
    d2 = *(const short8v*)(cp_ + 64);                                         \
    d3 = *(const short8v*)(cp_ + 96);                                         \
  }

#define EPILOGUE(TL, ACC, CN4, TOP)                                           \
  {                                                                           \
    int cb0_ = cbase + (TL) * 16 + hi * 4;                                    \
    float a0 = -(fminf(fmaxf(xn + (CN4).x - 2.0f * (ACC)[0], 1e-12f), 1e12f));\
    float a1 = -(fminf(fmaxf(xn + (CN4).y - 2.0f * (ACC)[1], 1e-12f), 1e12f));\
    float a2 = -(fminf(fmaxf(xn + (CN4).z - 2.0f * (ACC)[2], 1e-12f), 1e12f));\
    float a3 = -(fminf(fmaxf(xn + (CN4).w - 2.0f * (ACC)[3], 1e-12f), 1e12f));\
    bool l0 = (cb0_ + 0 == lab), l1 = (cb0_ + 1 == lab),                      \
         l2 = (cb0_ + 2 == lab), l3 = (cb0_ + 3 == lab);                      \
    posv = l0 ? a0 : posv; posv = l1 ? a1 : posv;                             \
    posv = l2 ? a2 : posv; posv = l3 ? a3 : posv;                             \
    a0 = l0 ? NEGINF : a0; a1 = l1 ? NEGINF : a1;                             \
    a2 = l2 ? NEGINF : a2; a3 = l3 ? NEGINF : a3;                             \
    SW(a0, a1) SW(a2, a3) SW(a0, a2) SW(a1, a3) SW(a1, a2)                    \
    float n0 = fmaxf(a0, TOP[0]);                                             \
    float n1 = fmaxf(fmaxf(a1, TOP[1]), fminf(a0, TOP[0]));                   \
    float n2 = fmaxf(fmaxf(a2, TOP[2]),                                       \
                     fmaxf(fminf(a0, TOP[1]), fminf(a1, TOP[0])));            \
    float n3 = fmaxf(fmaxf(a3, TOP[3]),                                       \
                     fmaxf(fmaxf(fminf(a0, TOP[2]), fminf(a1, TOP[1])),       \
                           fminf(a2, TOP[0])));                               \
    float n4 = fmaxf(TOP[4], fmaxf(fmaxf(fminf(a0, TOP[3]), fminf(a1, TOP[2])), \
                                   fmaxf(fminf(a2, TOP[1]), fminf(a3, TOP[0])))); \
    float n5 = fmaxf(TOP[5], fmaxf(fmaxf(fminf(a0, TOP[4]), fminf(a1, TOP[3])), \
                                   fmaxf(fminf(a2, TOP[2]), fminf(a3, TOP[1])))); \
    float n6 = fmaxf(TOP[6], fmaxf(fmaxf(fminf(a0, TOP[5]), fminf(a1, TOP[4])), \
                                   fmaxf(fminf(a2, TOP[3]), fminf(a3, TOP[2])))); \
    float n7 = fmaxf(TOP[7], fmaxf(fmaxf(fminf(a0, TOP[6]), fminf(a1, TOP[5])), \
                                   fmaxf(fminf(a2, TOP[4]), fminf(a3, TOP[3])))); \
    float n8 = fmaxf(TOP[8], fmaxf(fmaxf(fminf(a0, TOP[7]), fminf(a1, TOP[6])), \
                                   fmaxf(fminf(a2, TOP[5]), fminf(a3, TOP[4])))); \
    float n9 = fmaxf(TOP[9], fmaxf(fmaxf(fminf(a0, TOP[8]), fminf(a1, TOP[7])), \
                                   fmaxf(fminf(a2, TOP[6]), fminf(a3, TOP[5])))); \
    TOP[0] = n0; TOP[1] = n1; TOP[2] = n2; TOP[3] = n3; TOP[4] = n4;          \
    TOP[5] = n5; TOP[6] = n6; TOP[7] = n7; TOP[8] = n8; TOP[9] = n9;          \
  }

__global__ __launch_bounds__(256) void xloss_kernel(
    const int* __restrict__ labels, float* __restrict__ ws) {
  int t = threadIdx.x;
  int w = t >> 6, l = t & 63, lo = l & 15, hi = l >> 4;
  int row = blockIdx.x * 64 + w * 16 + lo;
  int cbase = blockIdx.y * CPS;

  const ushort* xb = (const ushort*)(ws + WS_XB);
  const ushort* cb = (const ushort*)(ws + WS_CB);

  const ushort* xrp = xb + (size_t)row * ND + hi * 8;
  short8v xf0 = *(const short8v*)(xrp + 0);
  short8v xf1 = *(const short8v*)(xrp + 32);
  short8v xf2 = *(const short8v*)(xrp + 64);
  short8v xf3 = *(const short8v*)(xrp + 96);

  float xn = ws[WS_XN + row];
  int lab = labels[row];

  float topA[10], topB[10];
#pragma unroll
  for (int k = 0; k < 10; ++k) { topA[k] = NEGINF; topB[k] = NEGINF; }
  float posv = NEGINF;

  short8v pa0, pa1, pa2, pa3, qa0, qa1, qa2, qa3;
  f32x4 cnP, cnQ;
  LOADF(pa0, pa1, pa2, pa3, 0)
  cnP = *(const f32x4*)(ws + WS_CN + cbase + hi * 4);

  for (int tl = 0; tl < NTILES; tl += 2) {
    LOADF(qa0, qa1, qa2, qa3, tl + 1)
    cnQ = *(const f32x4*)(ws + WS_CN + cbase + (tl + 1) * 16 + hi * 4);

    f32x4 aA1 = {0.f, 0.f, 0.f, 0.f}, aA2 = {0.f, 0.f, 0.f, 0.f};
    aA1 = __builtin_amdgcn_mfma_f32_16x16x32_bf16(pa0, xf0, aA1, 0, 0, 0);
    aA1 = __builtin_amdgcn_mfma_f32_16x16x32_bf16(pa1, xf1, aA1, 0, 0, 0);
    aA2 = __builtin_amdgcn_mfma_f32_16x16x32_bf16(pa2, xf2, aA2, 0, 0, 0);
    aA2 = __builtin_amdgcn_mfma_f32_16x16x32_bf16(pa3, xf3, aA2, 0, 0, 0);
    f32x4 accA = aA1 + aA2;
    f32x4 cnA = cnP;
    int nidx = (tl + 2 < NTILES) ? tl + 2 : tl;
    LOADF(pa0, pa1, pa2, pa3, nidx)
    cnP = *(const f32x4*)(ws + WS_CN + cbase + nidx * 16 + hi * 4);

    f32x4 aB1 = {0.f, 0.f, 0.f, 0.f}, aB2 = {0.f, 0.f, 0.f, 0.f};
    aB1 = __builtin_amdgcn_mfma_f32_16x16x32_bf16(qa0, xf0, aB1, 0, 0, 0);
    aB1 = __builtin_amdgcn_mfma_f32_16x16x32_bf16(qa1, xf1, aB1, 0, 0, 0);
    aB2 = __builtin_amdgcn_mfma_f32_16x16x32_bf16(qa2, xf2, aB2, 0, 0, 0);
    aB2 = __builtin_amdgcn_mfma_f32_16x16x32_bf16(qa3, xf3, aB2, 0, 0, 0);
    f32x4 accB = aB1 + aB2;

    EPILOGUE(tl, accA, cnA, topA)
    EPILOGUE(tl + 1, accB, cnQ, topB)
  }

#pragma unroll
  for (int k = 0; k < 10; ++k) INS10(topA, topB[k])

  float oth[10];
#pragma unroll
  for (int m = 16; m <= 32; m <<= 1) {
#pragma unroll
    for (int k = 0; k < 10; ++k) oth[k] = __shfl_xor(topA[k], m, 64);
#pragma unroll
    for (int k = 0; k < 10; ++k) INS10(topA, oth[k])
  }

  if (posv > -1.0e37f) ws[WS_POS + row] = posv;
  if (hi == 0) {
    float* dst = ws + WS_PART + ((size_t)row * NSPLIT + blockIdx.y) * 10;
#pragma unroll
    for (int k = 0; k < 10; ++k) dst[k] = topA[k];
  }
}

#define LOADB(d0, d1, d2, d3, GT)                                             \
  {                                                                           \
    const ushort* bp_ = cb + (size_t)((GT) * 16 + lo) * ND + hi * 8;          \
    d0 = *(const short8v*)(bp_ + 0);                                          \
    d1 = *(const short8v*)(bp_ + 32);                                         \
    d2 = *(const short8v*)(bp_ + 64);                                         \
    d3 = *(const short8v*)(bp_ + 96);                                         \
  }

#define C2CTILE(B0, B1, B2, B3, GT)                                           \
  {                                                                           \
    f32x4 c1_ = {0.f, 0.f, 0.f, 0.f}, c2_ = {0.f, 0.f, 0.f, 0.f};            \
    c1_ = __builtin_amdgcn_mfma_f32_16x16x32_bf16(B0, af0, c1_, 0, 0, 0);     \
    c1_ = __builtin_amdgcn_mfma_f32_16x16x32_bf16(B1, af1, c1_, 0, 0, 0);     \
    c2_ = __builtin_amdgcn_mfma_f32_16x16x32_bf16(B2, af2, c2_, 0, 0, 0);     \
    c2_ = __builtin_amdgcn_mfma_f32_16x16x32_bf16(B3, af3, c2_, 0, 0, 0);     \
    f32x4 ac_ = c1_ + c2_;                                                    \
    int gc0_ = (GT) * 16 + hi * 4;                                            \
    f32x4 cnj_ = *(const f32x4*)(ws + WS_CN + gc0_);                          \
    f32x4 dd_;                                                                \
    dd_[0] = fminf(fmaxf(cni + cnj_[0] - 2.0f * ac_[0], 1e-12f), 1e12f);      \
    dd_[1] = fminf(fmaxf(cni + cnj_[1] - 2.0f * ac_[1], 1e-12f), 1e12f);      \
    dd_[2] = fminf(fmaxf(cni + cnj_[2] - 2.0f * ac_[2], 1e-12f), 1e12f);      \
    dd_[3] = fminf(fmaxf(cni + cnj_[3] - 2.0f * ac_[3], 1e-12f), 1e12f);      \
    if (gc0_ + 3 < gr) {                                                      \
      tsum += dd_[0] + dd_[1] + dd_[2] + dd_[3];                              \
    } else if (gc0_ < gr) {                                                   \
      tsum += (gc0_ + 0 < gr) ? dd_[0] : 0.0f;                                \
      tsum += (gc0_ + 1 < gr) ? dd_[1] : 0.0f;                                \
      tsum += (gc0_ + 2 < gr) ? dd_[2] : 0.0f;                                \
      tsum += (gc0_ + 3 < gr) ? dd_[3] : 0.0f;                                \
    }                                                                         \
    *(f32x4*)(orow + gc0_) = dd_;                                             \
  }

// 512 blocks x 16 full rows: each block writes a 512KB contiguous slab, swept
// left->right (fill-like per-row sequential streams; one writer per row).
__global__ __launch_bounds__(256) void c2c_kernel(
    float* __restrict__ ws, float* __restrict__ outmat) {
  __shared__ float red[4];
  int t = threadIdx.x;
  int w = t >> 6, l = t & 63, lo = l & 15, hi = l >> 4;
  int rb = blockIdx.x * 16;
  int wt0 = w * 128;                     // wave's first col-tile (2048 cols/wave)
  const ushort* cb = (const ushort*)(ws + WS_CB);

  const ushort* ap = cb + (size_t)(rb + lo) * ND + hi * 8;
  short8v af0 = *(const short8v*)(ap + 0);
  short8v af1 = *(const short8v*)(ap + 32);
  short8v af2 = *(const short8v*)(ap + 64);
  short8v af3 = *(const short8v*)(ap + 96);

  int gr = rb + lo;
  float cni = ws[WS_CN + gr];
  float* orow = outmat + (size_t)gr * NC;
  float tsum = 0.0f;

  short8v p00, p01, p02, p03, p10, p11, p12, p13;
  short8v q00, q01, q02, q03, q10, q11, q12, q13;
  LOADB(p00, p01, p02, p03, wt0 + 0)
  LOADB(p10, p11, p12, p13, wt0 + 1)

  for (int ck = 0; ck < 64; ck += 2) {
    int gtQ = wt0 + (ck + 1) * 2;
    LOADB(q00, q01, q02, q03, gtQ + 0)
    LOADB(q10, q11, q12, q13, gtQ + 1)

    int gtP = wt0 + ck * 2;
    C2CTILE(p00, p01, p02, p03, gtP + 0)
    C2CTILE(p10, p11, p12, p13, gtP + 1)

    int nck = (ck + 2 < 64) ? ck + 2 : ck;
    int gtN = wt0 + nck * 2;
    LOADB(p00, p01, p02, p03, gtN + 0)
    LOADB(p10, p11, p12, p13, gtN + 1)

    C2CTILE(q00, q01, q02, q03, gtQ + 0)
    C2CTILE(q10, q11, q12, q13, gtQ + 1)
  }

#pragma unroll
  for (int off = 32; off; off >>= 1) tsum += __shfl_down(tsum, off, 64);
  if (l == 0) red[w] = tsum;
  __syncthreads();
  if (t == 0)
    atomicAdd(ws + 4 + (blockIdx.x % 12), red[0] + red[1] + red[2] + red[3]);
}

__global__ __launch_bounds__(256) void merge_fin_kernel(float* __restrict__ ws,
                                                        float* __restrict__ out) {
  int row = blockIdx.x * 256 + threadIdx.x;
  const f32x4* part = (const f32x4*)(ws + WS_PART + (size_t)row * NSPLIT * 10);
  float top[10];
#pragma unroll
  for (int k = 0; k < 10; ++k) top[k] = NEGINF;
#pragma unroll
  for (int i = 0; i < NSPLIT * 10 / 4; ++i) {
    f32x4 v = part[i];
    INS10(top, v.x)
    INS10(top, v.y)
    INS10(top, v.z)
    INS10(top, v.w)
  }
  float pos = ws[WS_POS + row];
  float mx = fmaxf(pos, top[0]);
  float ssum = expf(pos - mx);
#pragma unroll
  for (int k = 0; k < 10; ++k) ssum += expf(top[k] - mx);
  float lrow = mx + logf(ssum) - pos;
  float prow = -pos;
#pragma unroll
  for (int off = 32; off; off >>= 1) {
    lrow += __shfl_down(lrow, off, 64);
    prow += __shfl_down(prow, off, 64);
  }
  if ((threadIdx.x & 63) == 0) {
    atomicAdd(ws + 0, lrow);
    atomicAdd(ws + 2, prow);
  }
  __syncthreads();
  if (threadIdx.x == 0) {
    __threadfence();
    unsigned tk = atomicAdd((unsigned int*)(ws + 3), 1u);
    if (tk == 15u) {
      float ls = atomicAdd(ws + 0, 0.0f);
      float ps = atomicAdd(ws + 2, 0.0f);
      float ts = 0.0f;
#pragma unroll
      for (int i = 0; i < 12; ++i) ts += ws[4 + i];
      out[0] = ls / 4096.0f;
      out[1] = -ts / 33550336.0f;
      out[2 + (size_t)NC * NC] = ps / 4096.0f;
    }
  }
}

extern "C" void kernel_launch(void* const* d_in, const int* in_sizes, int n_in,
                              void* d_out, int out_size, void* d_ws, size_t ws_size,
                              hipStream_t stream) {
  const float* x = (const float*)d_in[0];
  const int* labels = (const int*)d_in[1];
  const float* centers = (const float*)d_in[2];
  float* out = (float*)d_out;
  float* ws = (float*)d_ws;

  hipLaunchKernelGGL(prep_kernel, dim3((NB + NC) / 4), dim3(256), 0, stream, x, centers, ws);
  hipLaunchKernelGGL(c2c_kernel, dim3(512), dim3(256), 0, stream, ws, out + 2);
  hipLaunchKernelGGL(xloss_kernel, dim3(64, NSPLIT), dim3(256), 0, stream, labels, ws);
  hipLaunchKernelGGL(merge_fin_kernel, dim3(NB / 256), dim3(256), 0, stream, ws, out);
}